// Round 2
// baseline (217.059 us; speedup 1.0000x reference)
//
#include <hip/hip_runtime.h>
#include <math.h>

constexpr int NFFT = 524288;   // 2^19 >= T + L - 1 = 485099
constexpr int N1   = 512;      // column FFT length (strided dim)
constexpr int N2   = 1024;     // row FFT length (contiguous dim)
constexpr int TT   = 441000;   // multiple of 4
constexpr int IRL  = 44100;    // multiple of 4
constexpr int NSIG = 16;       // 32 real batches packed as 16 complex signals
constexpr int C1   = 16;       // columns per block in stage1/3
constexpr int R2   = 4;        // rows per block in stage2

// -2*pi/NFFT
constexpr float ANG0   = -1.1984224905891939e-5f;
constexpr float NTWOPI = -6.2831853071795864769f;

// native clang vector type for nontemporal builtins (HIP float4 is a class)
typedef float vf4 __attribute__((ext_vector_type(4)));

__device__ inline float2 cmulf(float2 a, float2 b) {
    return make_float2(a.x * b.x - a.y * b.y, a.x * b.y + a.y * b.x);
}
__device__ inline float2 cadd(float2 a, float2 b) { return make_float2(a.x + b.x, a.y + b.y); }
__device__ inline float2 csub(float2 a, float2 b) { return make_float2(a.x - b.x, a.y - b.y); }

// Radix-4 Stockham butterfly (validated rounds 3-4). Outputs to q+4sp+{0,s,2s,3s},
// twiddles W^{ps},W^{2ps},W^{3ps}; cross term -i fwd / +i inv (caller conjugates w).
template<bool INV>
__device__ inline void bfly4(const float2* u, float2 w1, float2 w2, float2 w3, float2* o) {
    float2 t0 = cadd(u[0], u[2]);
    float2 t1 = csub(u[0], u[2]);
    float2 t2 = cadd(u[1], u[3]);
    float2 t3 = csub(u[1], u[3]);
    float2 r3 = INV ? make_float2(-t3.y, t3.x) : make_float2(t3.y, -t3.x);
    o[0] = cadd(t0, t2);
    o[1] = cmulf(cadd(t1, r3), w1);
    o[2] = cmulf(csub(t0, t2), w2);
    o[3] = cmulf(csub(t1, r3), w3);
}
// Unit-twiddle variant (s = L/4 final pass: p=0 -> w=1).
template<bool INV>
__device__ inline void bfly4_nw(const float2* u, float2* o) {
    float2 t0 = cadd(u[0], u[2]);
    float2 t1 = csub(u[0], u[2]);
    float2 t2 = cadd(u[1], u[3]);
    float2 t3 = csub(u[1], u[3]);
    float2 r3 = INV ? make_float2(-t3.y, t3.x) : make_float2(t3.y, -t3.x);
    o[0] = cadd(t0, t2);
    o[1] = cadd(t1, r3);
    o[2] = csub(t0, t2);
    o[3] = csub(t1, r3);
}

// First 4 radix-4 passes (s=1,4,16,64) of the 512-FFT over 16 XOR-swizzled
// sequences; 1024 threads: thread owns butterfly f = t&127 of seqs cb, cb+8.
template<bool INV>
__device__ void fft512_4p(float2* buf, const float2* __restrict__ tw, int tid) {
    const int f  = tid & 127;
    const int cb = tid >> 7;          // 0..7 (wave-uniform)
    int s = 1, logs = 0;
#pragma unroll
    for (int pass = 0; pass < 4; ++pass) {
        const int p = f >> logs;
        const int q = f & (s - 1);
        const int wb = q + 4 * s * p;
        const int e = p * s;
        float2 w1 = tw[e], w2 = tw[2 * e], w3 = tw[3 * e];
        if (INV) { w1.y = -w1.y; w2.y = -w2.y; w3.y = -w3.y; }
        float2 u[2][4];
#pragma unroll
        for (int k = 0; k < 2; ++k) {
            const int c = cb + 8 * k;
            float2* sb = buf + c * N1;
#pragma unroll
            for (int j = 0; j < 4; ++j) u[k][j] = sb[(f + 128 * j) ^ c];
        }
        __syncthreads();
#pragma unroll
        for (int k = 0; k < 2; ++k) {
            const int c = cb + 8 * k;
            float2* sb = buf + c * N1;
            float2 o[4];
            bfly4<INV>(u[k], w1, w2, w3, o);
            sb[wb ^ c]           = o[0];
            sb[(wb + s) ^ c]     = o[1];
            sb[(wb + 2 * s) ^ c] = o[2];
            sb[(wb + 3 * s) ^ c] = o[3];
        }
        __syncthreads();
        s <<= 2; logs += 2;
    }
}

// Radix-4 passes [FIRST, FIRST+COUNT) of the 1024-FFT over 4 rows; 1024
// threads: thread owns butterfly f = t&255 of row r = t>>8.
template<bool INV, int FIRST, int COUNT>
__device__ void fft1024_mid(float2* buf, const float2* __restrict__ tw, int tid) {
    const int f = tid & 255;
    const int r = tid >> 8;           // 0..3
    float2* sb = buf + r * N2;
    int s = 1 << (2 * FIRST), logs = 2 * FIRST;
#pragma unroll
    for (int pass = 0; pass < COUNT; ++pass) {
        const int p = f >> logs;
        const int q = f & (s - 1);
        const int wb = q + 4 * s * p;
        const int e = p * s;
        float2 w1 = tw[e], w2 = tw[2 * e], w3 = tw[3 * e];
        if (INV) { w1.y = -w1.y; w2.y = -w2.y; w3.y = -w3.y; }
        float2 u[4];
#pragma unroll
        for (int j = 0; j < 4; ++j) u[j] = sb[f + 256 * j];
        __syncthreads();
        float2 o[4];
        bfly4<INV>(u, w1, w2, w3, o);
        sb[wb]         = o[0];
        sb[wb + s]     = o[1];
        sb[wb + 2 * s] = o[2];
        sb[wb + 3 * s] = o[3];
        __syncthreads();
        s <<= 2; logs += 2;
    }
}

// Stage 1 (forward): 512-pt column FFTs (stride N2) for 16 consecutive n2 per
// block; float4 loads; final radix-2 fused with inter-stage twiddle + store.
__global__ __launch_bounds__(1024) void k_stage1(const float* __restrict__ x,
                                                 const float* __restrict__ ir,
                                                 float2* __restrict__ bufA,
                                                 float2* __restrict__ irA) {
    __shared__ float2 buf[C1 * N1];   // 64 KB
    __shared__ float2 tw[N1];         // 4 KB, W_512^j
    const int sig  = blockIdx.y;
    const int col0 = blockIdx.x * C1;
    const int tid  = threadIdx.x;

    if (tid < N1) {
        float sn, cs;
        __sincosf(NTWOPI * (float)tid * (1.0f / (float)N1), &sn, &cs);
        tw[tid] = make_float2(cs, sn);
    }

    if (sig < NSIG) {
        const float* xa = x + (size_t)(2 * sig) * TT;
        const float* xb = xa + TT;
#pragma unroll
        for (int it = 0; it < 2; ++it) {
            const int qi = tid + 1024 * it;     // 2048 quads
            const int n1 = qi >> 2;
            const int c4 = (qi & 3) * 4;
            const int n  = n1 * N2 + col0 + c4; // n % 4 == 0
            float4 a4 = make_float4(0.f, 0.f, 0.f, 0.f);
            float4 b4 = a4;
            if (n < TT) {
                a4 = *(const float4*)(xa + n);
                b4 = *(const float4*)(xb + n);
            }
            buf[(c4 + 0) * N1 + (n1 ^ (c4 + 0))] = make_float2(a4.x, b4.x);
            buf[(c4 + 1) * N1 + (n1 ^ (c4 + 1))] = make_float2(a4.y, b4.y);
            buf[(c4 + 2) * N1 + (n1 ^ (c4 + 2))] = make_float2(a4.z, b4.z);
            buf[(c4 + 3) * N1 + (n1 ^ (c4 + 3))] = make_float2(a4.w, b4.w);
        }
    } else {
#pragma unroll
        for (int it = 0; it < 2; ++it) {
            const int qi = tid + 1024 * it;
            const int n1 = qi >> 2;
            const int c4 = (qi & 3) * 4;
            const int n  = n1 * N2 + col0 + c4;
            float4 a4 = make_float4(0.f, 0.f, 0.f, 0.f);
            if (n < IRL) a4 = *(const float4*)(ir + n);
            buf[(c4 + 0) * N1 + (n1 ^ (c4 + 0))] = make_float2(a4.x, 0.f);
            buf[(c4 + 1) * N1 + (n1 ^ (c4 + 1))] = make_float2(a4.y, 0.f);
            buf[(c4 + 2) * N1 + (n1 ^ (c4 + 2))] = make_float2(a4.z, 0.f);
            buf[(c4 + 3) * N1 + (n1 ^ (c4 + 3))] = make_float2(a4.w, 0.f);
        }
    }
    __syncthreads();

    fft512_4p<false>(buf, tw, tid);

    // fused: final radix-2 (slots f / f+256) + W_N^{n2*k1} twiddle + store.
    // Twiddle recurrence: W^{n2(fr+64it)} = W^{n2*fr} * (W^{64n2})^it,
    // second output uses * W^{256n2}. All integer products < 2^24 (exact).
    float2* dst = (sig < NSIG) ? (bufA + (size_t)sig * NFFT) : irA;
    const int c  = tid & 15;
    const int fr = tid >> 4;          // 0..63
    const int n2 = col0 + c;
    float2 w0, s64, s256;
    {
        float sn, cs;
        __sincosf(ANG0 * (float)(n2 * fr), &sn, &cs);   w0   = make_float2(cs, sn);
        __sincosf(ANG0 * (float)(n2 * 64), &sn, &cs);   s64  = make_float2(cs, sn);
        __sincosf(ANG0 * (float)(n2 * 256), &sn, &cs);  s256 = make_float2(cs, sn);
    }
#pragma unroll
    for (int it = 0; it < 4; ++it) {
        const int fo = fr + 64 * it;  // 0..255
        float2 a = buf[c * N1 + (fo ^ c)];
        float2 b = buf[c * N1 + ((fo + 256) ^ c)];
        float2 X0 = cadd(a, b);
        float2 X1 = csub(a, b);
        dst[(size_t)fo * N2 + n2]         = cmulf(X0, w0);
        dst[(size_t)(fo + 256) * N2 + n2] = cmulf(X1, cmulf(w0, s256));
        w0 = cmulf(w0, s64);
    }
}

// Stage 2, IR path: forward 1024-FFT only -> Ht (transposed spectrum).
__global__ __launch_bounds__(1024) void k_stage2_ir(const float2* __restrict__ src,
                                                    float2* __restrict__ dst) {
    __shared__ float2 buf[R2 * N2];   // 32 KB
    __shared__ float2 tw[N2];         // 8 KB, W_1024^j
    const int r0  = blockIdx.x * R2;
    const int tid = threadIdx.x;

    {
        float sn, cs;
        __sincosf(NTWOPI * (float)tid * (1.0f / (float)N2), &sn, &cs);
        tw[tid] = make_float2(cs, sn);
    }
#pragma unroll
    for (int it = 0; it < 2; ++it) {
        const int qi = tid + 1024 * it;   // 2048 float4
        ((float4*)buf)[qi] = ((const float4*)src)[(size_t)r0 * (N2 / 2) + qi];
    }
    __syncthreads();

    fft1024_mid<false, 0, 4>(buf, tw, tid);

    const int f = tid & 255;
    const int r = tid >> 8;
    float2 u[4], o[4];
#pragma unroll
    for (int j = 0; j < 4; ++j) u[j] = buf[r * N2 + f + 256 * j];
    bfly4_nw<false>(u, o);
#pragma unroll
    for (int j = 0; j < 4; ++j)
        dst[(size_t)(r0 + r) * N2 + f + 256 * j] = o[j];
}

// Stage 2: fwd 1024-FFT, * Ht, inv 1024-FFT, conj inter-stage twiddle, store.
// fwd-pass5 + Ht-mult + inv-pass1 fused in registers.
// IN-PLACE safe (dst may == src): each block reads its 4 exclusively-owned
// rows fully into LDS before any global write to those rows.
__global__ __launch_bounds__(1024) void k_stage2(const float2* __restrict__ src,
                                                 float2* __restrict__ dst,
                                                 const float2* __restrict__ Ht) {
    __shared__ float2 buf[R2 * N2];   // 32 KB
    __shared__ float2 tw[N2];         // 8 KB
    const int r0  = blockIdx.x * R2;  // flat row = sig*N1 + k1
    const int tid = threadIdx.x;

    {
        float sn, cs;
        __sincosf(NTWOPI * (float)tid * (1.0f / (float)N2), &sn, &cs);
        tw[tid] = make_float2(cs, sn);
    }
#pragma unroll
    for (int it = 0; it < 2; ++it) {
        const int qi = tid + 1024 * it;
        ((float4*)buf)[qi] = ((const float4*)src)[(size_t)r0 * (N2 / 2) + qi];
    }
    __syncthreads();

    fft1024_mid<false, 0, 4>(buf, tw, tid);

    const int f  = tid & 255;
    const int r  = tid >> 8;
    const int k1 = (r0 + r) & (N1 - 1);
    {   // fwd p4 (unit tw) -> * Ht -> inv p0 (conj W_1024^{f,2f,3f}), in regs
        float2 u[4], h[4];
#pragma unroll
        for (int j = 0; j < 4; ++j) {
            u[j] = buf[r * N2 + f + 256 * j];
            h[j] = Ht[(size_t)k1 * N2 + f + 256 * j];
        }
        __syncthreads();   // WAR guard
        float2 w1 = tw[f], w2 = tw[2 * f], w3 = tw[3 * f];
        w1.y = -w1.y; w2.y = -w2.y; w3.y = -w3.y;
        float2 o[4], v[4], o2[4];
        bfly4_nw<false>(u, o);
#pragma unroll
        for (int j = 0; j < 4; ++j) v[j] = cmulf(o[j], h[j]);
        bfly4<true>(v, w1, w2, w3, o2);
        float2* sb = buf + r * N2;
#pragma unroll
        for (int j = 0; j < 4; ++j) sb[4 * f + j] = o2[j];   // wb=4f, s=1
        __syncthreads();
    }

    fft1024_mid<true, 1, 3>(buf, tw, tid);   // inv passes s=4,16,64

    // inv final pass (s=256, unit tw) + conj twiddle recurrence + store:
    // W^{-k1(f+256j)} = W^{-k1 f} * (W^{-256 k1})^j
    float2 u[4], o[4];
#pragma unroll
    for (int j = 0; j < 4; ++j) u[j] = buf[r * N2 + f + 256 * j];
    bfly4_nw<true>(u, o);
    float2 w, st;
    {
        float sn, cs;
        __sincosf(-ANG0 * (float)(f * k1), &sn, &cs);   w  = make_float2(cs, sn);
        __sincosf(-ANG0 * (float)(256 * k1), &sn, &cs); st = make_float2(cs, sn);
    }
#pragma unroll
    for (int j = 0; j < 4; ++j) {
        dst[(size_t)(r0 + r) * N2 + f + 256 * j] = cmulf(o[j], w);
        w = cmulf(w, st);
    }
}

// Stage 3 (inverse): 512-pt column IFFTs; final radix-2 fused with unpack,
// wet/dry mix and float4 stores. Output stores are non-temporal: `out` is
// write-once/never-read, keep it from evicting x/bufA from Infinity Cache.
__global__ __launch_bounds__(1024) void k_stage3(const float2* __restrict__ bufB,
                                                 const float* __restrict__ x,
                                                 const float* __restrict__ wet_param,
                                                 float* __restrict__ out) {
    __shared__ float2 buf[C1 * N1];   // 64 KB
    __shared__ float2 tw[N1];         // 4 KB
    const int sig  = blockIdx.y;
    const int col0 = blockIdx.x * C1;
    const int tid  = threadIdx.x;

    if (tid < N1) {
        float sn, cs;
        __sincosf(NTWOPI * (float)tid * (1.0f / (float)N1), &sn, &cs);
        tw[tid] = make_float2(cs, sn);
    }

    const float2* src = bufB + (size_t)sig * NFFT;
    {
        const int cp  = tid & 7;      // column pair (1 float4)
        const int k1b = tid >> 3;     // 0..127
#pragma unroll
        for (int it = 0; it < 4; ++it) {
            const int k1 = k1b + 128 * it;
            float4 v = *(const float4*)(src + (size_t)k1 * N2 + col0 + 2 * cp);
            const int ca = 2 * cp, cb2 = 2 * cp + 1;
            buf[ca * N1 + (k1 ^ ca)]   = make_float2(v.x, v.y);
            buf[cb2 * N1 + (k1 ^ cb2)] = make_float2(v.z, v.w);
        }
    }
    __syncthreads();

    fft512_4p<true>(buf, tw, tid);

    const float wet = 1.0f / (1.0f + expf(-wet_param[0]));
    const float dry = 1.0f - wet;
    const float ws  = wet * (1.0f / (float)NFFT);

    const float* xa = x + (size_t)(2 * sig) * TT;
    const float* xb = xa + TT;
    float* oa = out + (size_t)(2 * sig) * TT;
    float* ob = oa + TT;

    const int c4 = (tid & 3) * 4;
    const int fo = tid >> 2;          // 0..255
    float2 y0[4], y1[4];
#pragma unroll
    for (int jj = 0; jj < 4; ++jj) {
        const int c = c4 + jj;
        float2 a = buf[c * N1 + (fo ^ c)];
        float2 b = buf[c * N1 + ((fo + 256) ^ c)];
        y0[jj] = cadd(a, b);          // time row fo
        y1[jj] = csub(a, b);          // time row fo+256
    }
#pragma unroll
    for (int h = 0; h < 2; ++h) {
        const int row = fo + 256 * h;
        const int n   = row * N2 + col0 + c4;   // n % 4 == 0
        if (n < TT) {
            const float2* yy = h ? y1 : y0;
            float4 a4 = *(const float4*)(xa + n);
            float4 b4 = *(const float4*)(xb + n);
            vf4 ra, rb2;
            ra.x = dry * a4.x + ws * yy[0].x;
            ra.y = dry * a4.y + ws * yy[1].x;
            ra.z = dry * a4.z + ws * yy[2].x;
            ra.w = dry * a4.w + ws * yy[3].x;
            rb2.x = dry * b4.x + ws * yy[0].y;
            rb2.y = dry * b4.y + ws * yy[1].y;
            rb2.z = dry * b4.z + ws * yy[2].y;
            rb2.w = dry * b4.w + ws * yy[3].y;
            __builtin_nontemporal_store(ra,  (vf4*)(oa + n));
            __builtin_nontemporal_store(rb2, (vf4*)(ob + n));
        }
    }
}

// Correctness fallback if workspace is too small: direct time-domain conv.
__global__ __launch_bounds__(256) void k_direct(const float* __restrict__ x,
                                                const float* __restrict__ ir,
                                                const float* __restrict__ wet_param,
                                                float* __restrict__ out) {
    __shared__ float irs[1024];
    const int b = blockIdx.y;
    const int n = blockIdx.x * 256 + threadIdx.x;
    float acc = 0.0f;
    for (int k0 = 0; k0 < IRL; k0 += 1024) {
        __syncthreads();
        for (int j = threadIdx.x; j < 1024; j += 256) {
            const int k = k0 + j;
            irs[j] = (k < IRL) ? ir[k] : 0.0f;
        }
        __syncthreads();
        if (n < TT) {
            const int kend = min(1024, n - k0 + 1);
            for (int k = 0; k < kend; ++k)
                acc += irs[k] * x[(size_t)b * TT + (n - k0 - k)];
        }
    }
    if (n < TT) {
        const float wet = 1.0f / (1.0f + expf(-wet_param[0]));
        out[(size_t)b * TT + n] = (1.0f - wet) * x[(size_t)b * TT + n] + wet * acc;
    }
}

extern "C" void kernel_launch(void* const* d_in, const int* in_sizes, int n_in,
                              void* d_out, int out_size, void* d_ws, size_t ws_size,
                              hipStream_t stream) {
    (void)in_sizes; (void)n_in; (void)out_size;
    const float* x   = (const float*)d_in[0];
    const float* ir  = (const float*)d_in[1];
    const float* wet = (const float*)d_in[2];
    float* out = (float*)d_out;

    // ws: Ht(NFFT) + irA(NFFT) + bufA(16*NFFT); stage2 runs IN-PLACE on bufA
    // so the live read footprint (x 56MB + bufA 64MB + Ht/irA 8MB) fits the
    // 256 MB Infinity Cache with room to spare.
    const size_t need = (size_t)(2 + NSIG) * (size_t)NFFT * sizeof(float2);
    if (ws_size < need) {
        dim3 g((TT + 255) / 256, 32);
        k_direct<<<g, 256, 0, stream>>>(x, ir, wet, out);
        return;
    }

    float2* Ht   = (float2*)d_ws;
    float2* irA  = Ht + NFFT;
    float2* bufA = irA + NFFT;

    k_stage1<<<dim3(N2 / C1, NSIG + 1), 1024, 0, stream>>>(x, ir, bufA, irA);
    k_stage2_ir<<<dim3(N1 / R2), 1024, 0, stream>>>(irA, Ht);
    k_stage2<<<dim3(NSIG * N1 / R2), 1024, 0, stream>>>(bufA, bufA, Ht);
    k_stage3<<<dim3(N2 / C1, NSIG), 1024, 0, stream>>>(bufA, x, wet, out);
}

// Round 3
// 212.515 us; speedup vs baseline: 1.0214x; 1.0214x over previous
//
#include <hip/hip_runtime.h>
#include <math.h>

constexpr int NFFT = 524288;   // 2^19 >= T + L - 1 = 485099
constexpr int N1   = 512;      // column FFT length (strided dim)
constexpr int N2   = 1024;     // row FFT length (contiguous dim)
constexpr int TT   = 441000;   // multiple of 4
constexpr int IRL  = 44100;    // multiple of 4
constexpr int NSIG = 16;       // 32 real batches packed as 16 complex signals
constexpr int C1   = 16;       // columns per block in stage1/3
constexpr int R2   = 4;        // rows per block in stage2
constexpr int TILE = N1 * C1;  // 8192 complex: one (all-k1 x 16-n2) tile

// bufA/irA layout is TILED: addr = (n2/16)*TILE + k1*16 + (n2%16).
// Writer (stage1) and readers (stage2 gather, stage3 full tile) all touch
// >=128B contiguous segments -> full HBM lines. Ht stays row-major [k1][n2].

// -2*pi/NFFT
constexpr float ANG0   = -1.1984224905891939e-5f;
constexpr float NTWOPI = -6.2831853071795864769f;

__device__ inline float2 cmulf(float2 a, float2 b) {
    return make_float2(a.x * b.x - a.y * b.y, a.x * b.y + a.y * b.x);
}
__device__ inline float2 cadd(float2 a, float2 b) { return make_float2(a.x + b.x, a.y + b.y); }
__device__ inline float2 csub(float2 a, float2 b) { return make_float2(a.x - b.x, a.y - b.y); }

// Radix-4 Stockham butterfly (validated). Outputs to q+4sp+{0,s,2s,3s},
// twiddles W^{ps},W^{2ps},W^{3ps}; cross term -i fwd / +i inv (caller conjugates w).
template<bool INV>
__device__ inline void bfly4(const float2* u, float2 w1, float2 w2, float2 w3, float2* o) {
    float2 t0 = cadd(u[0], u[2]);
    float2 t1 = csub(u[0], u[2]);
    float2 t2 = cadd(u[1], u[3]);
    float2 t3 = csub(u[1], u[3]);
    float2 r3 = INV ? make_float2(-t3.y, t3.x) : make_float2(t3.y, -t3.x);
    o[0] = cadd(t0, t2);
    o[1] = cmulf(cadd(t1, r3), w1);
    o[2] = cmulf(csub(t0, t2), w2);
    o[3] = cmulf(csub(t1, r3), w3);
}
// Unit-twiddle variant (s = L/4 final pass: p=0 -> w=1).
template<bool INV>
__device__ inline void bfly4_nw(const float2* u, float2* o) {
    float2 t0 = cadd(u[0], u[2]);
    float2 t1 = csub(u[0], u[2]);
    float2 t2 = cadd(u[1], u[3]);
    float2 t3 = csub(u[1], u[3]);
    float2 r3 = INV ? make_float2(-t3.y, t3.x) : make_float2(t3.y, -t3.x);
    o[0] = cadd(t0, t2);
    o[1] = cadd(t1, r3);
    o[2] = csub(t0, t2);
    o[3] = csub(t1, r3);
}

// First 4 radix-4 passes (s=1,4,16,64) of the 512-FFT over 16 XOR-swizzled
// sequences; 1024 threads: thread owns butterfly f = t&127 of seqs cb, cb+8.
template<bool INV>
__device__ void fft512_4p(float2* buf, const float2* __restrict__ tw, int tid) {
    const int f  = tid & 127;
    const int cb = tid >> 7;          // 0..7 (wave-uniform)
    int s = 1, logs = 0;
#pragma unroll
    for (int pass = 0; pass < 4; ++pass) {
        const int p = f >> logs;
        const int q = f & (s - 1);
        const int wb = q + 4 * s * p;
        const int e = p * s;
        float2 w1 = tw[e], w2 = tw[2 * e], w3 = tw[3 * e];
        if (INV) { w1.y = -w1.y; w2.y = -w2.y; w3.y = -w3.y; }
        float2 u[2][4];
#pragma unroll
        for (int k = 0; k < 2; ++k) {
            const int c = cb + 8 * k;
            float2* sb = buf + c * N1;
#pragma unroll
            for (int j = 0; j < 4; ++j) u[k][j] = sb[(f + 128 * j) ^ c];
        }
        __syncthreads();
#pragma unroll
        for (int k = 0; k < 2; ++k) {
            const int c = cb + 8 * k;
            float2* sb = buf + c * N1;
            float2 o[4];
            bfly4<INV>(u[k], w1, w2, w3, o);
            sb[wb ^ c]           = o[0];
            sb[(wb + s) ^ c]     = o[1];
            sb[(wb + 2 * s) ^ c] = o[2];
            sb[(wb + 3 * s) ^ c] = o[3];
        }
        __syncthreads();
        s <<= 2; logs += 2;
    }
}

// Radix-4 passes [FIRST, FIRST+COUNT) of the 1024-FFT over 4 rows; 1024
// threads: thread owns butterfly f = t&255 of row r = t>>8.
template<bool INV, int FIRST, int COUNT>
__device__ void fft1024_mid(float2* buf, const float2* __restrict__ tw, int tid) {
    const int f = tid & 255;
    const int r = tid >> 8;           // 0..3
    float2* sb = buf + r * N2;
    int s = 1 << (2 * FIRST), logs = 2 * FIRST;
#pragma unroll
    for (int pass = 0; pass < COUNT; ++pass) {
        const int p = f >> logs;
        const int q = f & (s - 1);
        const int wb = q + 4 * s * p;
        const int e = p * s;
        float2 w1 = tw[e], w2 = tw[2 * e], w3 = tw[3 * e];
        if (INV) { w1.y = -w1.y; w2.y = -w2.y; w3.y = -w3.y; }
        float2 u[4];
#pragma unroll
        for (int j = 0; j < 4; ++j) u[j] = sb[f + 256 * j];
        __syncthreads();
        float2 o[4];
        bfly4<INV>(u, w1, w2, w3, o);
        sb[wb]         = o[0];
        sb[wb + s]     = o[1];
        sb[wb + 2 * s] = o[2];
        sb[wb + 3 * s] = o[3];
        __syncthreads();
        s <<= 2; logs += 2;
    }
}

// Stage 1 (forward): 512-pt column FFTs (stride N2) for 16 consecutive n2 per
// block; float4 loads; final radix-2 fused with inter-stage twiddle + store.
// Stores to the TILED layout: this block's tile is contiguous (64 KB).
__global__ __launch_bounds__(1024) void k_stage1(const float* __restrict__ x,
                                                 const float* __restrict__ ir,
                                                 float2* __restrict__ bufA,
                                                 float2* __restrict__ irA) {
    __shared__ float2 buf[C1 * N1];   // 64 KB
    __shared__ float2 tw[N1];         // 4 KB, W_512^j
    const int sig  = blockIdx.y;
    const int col0 = blockIdx.x * C1;
    const int tid  = threadIdx.x;

    if (tid < N1) {
        float sn, cs;
        __sincosf(NTWOPI * (float)tid * (1.0f / (float)N1), &sn, &cs);
        tw[tid] = make_float2(cs, sn);
    }

    if (sig < NSIG) {
        const float* xa = x + (size_t)(2 * sig) * TT;
        const float* xb = xa + TT;
#pragma unroll
        for (int it = 0; it < 2; ++it) {
            const int qi = tid + 1024 * it;     // 2048 quads
            const int n1 = qi >> 2;
            const int c4 = (qi & 3) * 4;
            const int n  = n1 * N2 + col0 + c4; // n % 4 == 0
            float4 a4 = make_float4(0.f, 0.f, 0.f, 0.f);
            float4 b4 = a4;
            if (n < TT) {
                a4 = *(const float4*)(xa + n);
                b4 = *(const float4*)(xb + n);
            }
            buf[(c4 + 0) * N1 + (n1 ^ (c4 + 0))] = make_float2(a4.x, b4.x);
            buf[(c4 + 1) * N1 + (n1 ^ (c4 + 1))] = make_float2(a4.y, b4.y);
            buf[(c4 + 2) * N1 + (n1 ^ (c4 + 2))] = make_float2(a4.z, b4.z);
            buf[(c4 + 3) * N1 + (n1 ^ (c4 + 3))] = make_float2(a4.w, b4.w);
        }
    } else {
#pragma unroll
        for (int it = 0; it < 2; ++it) {
            const int qi = tid + 1024 * it;
            const int n1 = qi >> 2;
            const int c4 = (qi & 3) * 4;
            const int n  = n1 * N2 + col0 + c4;
            float4 a4 = make_float4(0.f, 0.f, 0.f, 0.f);
            if (n < IRL) a4 = *(const float4*)(ir + n);
            buf[(c4 + 0) * N1 + (n1 ^ (c4 + 0))] = make_float2(a4.x, 0.f);
            buf[(c4 + 1) * N1 + (n1 ^ (c4 + 1))] = make_float2(a4.y, 0.f);
            buf[(c4 + 2) * N1 + (n1 ^ (c4 + 2))] = make_float2(a4.z, 0.f);
            buf[(c4 + 3) * N1 + (n1 ^ (c4 + 3))] = make_float2(a4.w, 0.f);
        }
    }
    __syncthreads();

    fft512_4p<false>(buf, tw, tid);

    // fused: final radix-2 (slots f / f+256) + W_N^{n2*k1} twiddle + store.
    // Twiddle recurrence: W^{n2(fr+64it)} = W^{n2*fr} * (W^{64n2})^it,
    // second output uses * W^{256n2}. All integer products < 2^24 (exact).
    float2* dst = (sig < NSIG) ? (bufA + (size_t)sig * NFFT) : irA;
    float2* dstt = dst + (size_t)blockIdx.x * TILE;   // this block's tile
    const int c  = tid & 15;
    const int fr = tid >> 4;          // 0..63
    const int n2 = col0 + c;
    float2 w0, s64, s256;
    {
        float sn, cs;
        __sincosf(ANG0 * (float)(n2 * fr), &sn, &cs);   w0   = make_float2(cs, sn);
        __sincosf(ANG0 * (float)(n2 * 64), &sn, &cs);   s64  = make_float2(cs, sn);
        __sincosf(ANG0 * (float)(n2 * 256), &sn, &cs);  s256 = make_float2(cs, sn);
    }
#pragma unroll
    for (int it = 0; it < 4; ++it) {
        const int fo = fr + 64 * it;  // 0..255
        float2 a = buf[c * N1 + (fo ^ c)];
        float2 b = buf[c * N1 + ((fo + 256) ^ c)];
        float2 X0 = cadd(a, b);
        float2 X1 = csub(a, b);
        dstt[fo * C1 + c]         = cmulf(X0, w0);
        dstt[(fo + 256) * C1 + c] = cmulf(X1, cmulf(w0, s256));
        w0 = cmulf(w0, s64);
    }
}

// Stage 2, IR path: forward 1024-FFT only -> Ht (transposed spectrum, row-major).
// Reads irA in TILED layout.
__global__ __launch_bounds__(1024) void k_stage2_ir(const float2* __restrict__ src,
                                                    float2* __restrict__ dst) {
    __shared__ float2 buf[R2 * N2];   // 32 KB
    __shared__ float2 tw[N2];         // 8 KB, W_1024^j
    const int r0  = blockIdx.x * R2;
    const int tid = threadIdx.x;

    {
        float sn, cs;
        __sincosf(NTWOPI * (float)tid * (1.0f / (float)N2), &sn, &cs);
        tw[tid] = make_float2(cs, sn);
    }
#pragma unroll
    for (int it = 0; it < 2; ++it) {
        const int qi   = tid + 1024 * it;   // 2048 float4 (= 4 rows x 512)
        const int r    = qi >> 9;           // row within block
        const int np   = qi & 511;          // float4 index within row
        const int tile = np >> 3;           // 0..63
        const int q8   = np & 7;            // float4 within tile-row (128B seg)
        const int k1   = r0 + r;
        ((float4*)buf)[qi] =
            ((const float4*)src)[(size_t)tile * (TILE / 2) + k1 * 8 + q8];
    }
    __syncthreads();

    fft1024_mid<false, 0, 4>(buf, tw, tid);

    const int f = tid & 255;
    const int r = tid >> 8;
    float2 u[4], o[4];
#pragma unroll
    for (int j = 0; j < 4; ++j) u[j] = buf[r * N2 + f + 256 * j];
    bfly4_nw<false>(u, o);
#pragma unroll
    for (int j = 0; j < 4; ++j)
        dst[(size_t)(r0 + r) * N2 + f + 256 * j] = o[j];
}

// Stage 2: fwd 1024-FFT, * Ht, inv 1024-FFT, conj inter-stage twiddle, store.
// fwd-pass5 + Ht-mult + inv-pass1 fused in registers.
// IN-PLACE safe (dst may == src): each block reads its 4 exclusively-owned
// rows fully into LDS before any global write to those rows.
// src/dst use the TILED per-signal layout; Ht is row-major.
__global__ __launch_bounds__(1024) void k_stage2(const float2* __restrict__ src,
                                                 float2* __restrict__ dst,
                                                 const float2* __restrict__ Ht) {
    __shared__ float2 buf[R2 * N2];   // 32 KB
    __shared__ float2 tw[N2];         // 8 KB
    const int r0  = blockIdx.x * R2;  // flat row = sig*N1 + k1
    const int tid = threadIdx.x;

    {
        float sn, cs;
        __sincosf(NTWOPI * (float)tid * (1.0f / (float)N2), &sn, &cs);
        tw[tid] = make_float2(cs, sn);
    }
#pragma unroll
    for (int it = 0; it < 2; ++it) {
        const int qi   = tid + 1024 * it;
        const int r    = qi >> 9;
        const int np   = qi & 511;
        const int tile = np >> 3;
        const int q8   = np & 7;
        const int flat = r0 + r;
        const int sg   = flat >> 9;         // signal
        const int k1r  = flat & (N1 - 1);   // k1 within signal
        ((float4*)buf)[qi] =
            ((const float4*)src)[(size_t)sg * (NFFT / 2) +
                                 (size_t)tile * (TILE / 2) + k1r * 8 + q8];
    }
    __syncthreads();

    fft1024_mid<false, 0, 4>(buf, tw, tid);

    const int f  = tid & 255;
    const int r  = tid >> 8;
    const int k1 = (r0 + r) & (N1 - 1);
    {   // fwd p4 (unit tw) -> * Ht -> inv p0 (conj W_1024^{f,2f,3f}), in regs
        float2 u[4], h[4];
#pragma unroll
        for (int j = 0; j < 4; ++j) {
            u[j] = buf[r * N2 + f + 256 * j];
            h[j] = Ht[(size_t)k1 * N2 + f + 256 * j];
        }
        __syncthreads();   // WAR guard
        float2 w1 = tw[f], w2 = tw[2 * f], w3 = tw[3 * f];
        w1.y = -w1.y; w2.y = -w2.y; w3.y = -w3.y;
        float2 o[4], v[4], o2[4];
        bfly4_nw<false>(u, o);
#pragma unroll
        for (int j = 0; j < 4; ++j) v[j] = cmulf(o[j], h[j]);
        bfly4<true>(v, w1, w2, w3, o2);
        float2* sb = buf + r * N2;
#pragma unroll
        for (int j = 0; j < 4; ++j) sb[4 * f + j] = o2[j];   // wb=4f, s=1
        __syncthreads();
    }

    fft1024_mid<true, 1, 3>(buf, tw, tid);   // inv passes s=4,16,64

    // inv final pass (s=256, unit tw) + conj twiddle recurrence + store:
    // W^{-k1(f+256j)} = W^{-k1 f} * (W^{-256 k1})^j
    float2 u[4], o[4];
#pragma unroll
    for (int j = 0; j < 4; ++j) u[j] = buf[r * N2 + f + 256 * j];
    bfly4_nw<true>(u, o);
    float2 w, st;
    {
        float sn, cs;
        __sincosf(-ANG0 * (float)(f * k1), &sn, &cs);   w  = make_float2(cs, sn);
        __sincosf(-ANG0 * (float)(256 * k1), &sn, &cs); st = make_float2(cs, sn);
    }
    const int sg = (r0 + r) >> 9;
    float2* db = dst + (size_t)sg * NFFT;
#pragma unroll
    for (int j = 0; j < 4; ++j) {
        const int n2 = f + 256 * j;
        db[(size_t)(n2 >> 4) * TILE + k1 * C1 + (n2 & 15)] = cmulf(o[j], w);
        w = cmulf(w, st);
    }
}

// Stage 3 (inverse): 512-pt column IFFTs; final radix-2 fused with unpack,
// wet/dry mix and float4 stores. Reads its TILED bufA tile fully contiguously.
__global__ __launch_bounds__(1024) void k_stage3(const float2* __restrict__ bufB,
                                                 const float* __restrict__ x,
                                                 const float* __restrict__ wet_param,
                                                 float* __restrict__ out) {
    __shared__ float2 buf[C1 * N1];   // 64 KB
    __shared__ float2 tw[N1];         // 4 KB
    const int sig  = blockIdx.y;
    const int col0 = blockIdx.x * C1;
    const int tid  = threadIdx.x;

    if (tid < N1) {
        float sn, cs;
        __sincosf(NTWOPI * (float)tid * (1.0f / (float)N1), &sn, &cs);
        tw[tid] = make_float2(cs, sn);
    }

    const float2* st = bufB + (size_t)sig * NFFT + (size_t)blockIdx.x * TILE;
    {
        const int cp  = tid & 7;      // float4 within tile-row
        const int k1b = tid >> 3;     // 0..127
#pragma unroll
        for (int it = 0; it < 4; ++it) {
            const int k1 = k1b + 128 * it;
            float4 v = ((const float4*)st)[k1 * 8 + cp];   // contiguous tile
            const int ca = 2 * cp, cb2 = 2 * cp + 1;
            buf[ca * N1 + (k1 ^ ca)]   = make_float2(v.x, v.y);
            buf[cb2 * N1 + (k1 ^ cb2)] = make_float2(v.z, v.w);
        }
    }
    __syncthreads();

    fft512_4p<true>(buf, tw, tid);

    const float wet = 1.0f / (1.0f + expf(-wet_param[0]));
    const float dry = 1.0f - wet;
    const float ws  = wet * (1.0f / (float)NFFT);

    const float* xa = x + (size_t)(2 * sig) * TT;
    const float* xb = xa + TT;
    float* oa = out + (size_t)(2 * sig) * TT;
    float* ob = oa + TT;

    const int c4 = (tid & 3) * 4;
    const int fo = tid >> 2;          // 0..255
    float2 y0[4], y1[4];
#pragma unroll
    for (int jj = 0; jj < 4; ++jj) {
        const int c = c4 + jj;
        float2 a = buf[c * N1 + (fo ^ c)];
        float2 b = buf[c * N1 + ((fo + 256) ^ c)];
        y0[jj] = cadd(a, b);          // time row fo
        y1[jj] = csub(a, b);          // time row fo+256
    }
#pragma unroll
    for (int h = 0; h < 2; ++h) {
        const int row = fo + 256 * h;
        const int n   = row * N2 + col0 + c4;   // n % 4 == 0
        if (n < TT) {
            const float2* yy = h ? y1 : y0;
            float4 a4 = *(const float4*)(xa + n);
            float4 b4 = *(const float4*)(xb + n);
            float4 ra, rb2;
            ra.x = dry * a4.x + ws * yy[0].x;
            ra.y = dry * a4.y + ws * yy[1].x;
            ra.z = dry * a4.z + ws * yy[2].x;
            ra.w = dry * a4.w + ws * yy[3].x;
            rb2.x = dry * b4.x + ws * yy[0].y;
            rb2.y = dry * b4.y + ws * yy[1].y;
            rb2.z = dry * b4.z + ws * yy[2].y;
            rb2.w = dry * b4.w + ws * yy[3].y;
            *(float4*)(oa + n) = ra;
            *(float4*)(ob + n) = rb2;
        }
    }
}

// Correctness fallback if workspace is too small: direct time-domain conv.
__global__ __launch_bounds__(256) void k_direct(const float* __restrict__ x,
                                                const float* __restrict__ ir,
                                                const float* __restrict__ wet_param,
                                                float* __restrict__ out) {
    __shared__ float irs[1024];
    const int b = blockIdx.y;
    const int n = blockIdx.x * 256 + threadIdx.x;
    float acc = 0.0f;
    for (int k0 = 0; k0 < IRL; k0 += 1024) {
        __syncthreads();
        for (int j = threadIdx.x; j < 1024; j += 256) {
            const int k = k0 + j;
            irs[j] = (k < IRL) ? ir[k] : 0.0f;
        }
        __syncthreads();
        if (n < TT) {
            const int kend = min(1024, n - k0 + 1);
            for (int k = 0; k < kend; ++k)
                acc += irs[k] * x[(size_t)b * TT + (n - k0 - k)];
        }
    }
    if (n < TT) {
        const float wet = 1.0f / (1.0f + expf(-wet_param[0]));
        out[(size_t)b * TT + n] = (1.0f - wet) * x[(size_t)b * TT + n] + wet * acc;
    }
}

extern "C" void kernel_launch(void* const* d_in, const int* in_sizes, int n_in,
                              void* d_out, int out_size, void* d_ws, size_t ws_size,
                              hipStream_t stream) {
    (void)in_sizes; (void)n_in; (void)out_size;
    const float* x   = (const float*)d_in[0];
    const float* ir  = (const float*)d_in[1];
    const float* wet = (const float*)d_in[2];
    float* out = (float*)d_out;

    // ws: Ht(NFFT) + irA(NFFT) + bufA(16*NFFT); stage2 runs IN-PLACE on bufA.
    const size_t need = (size_t)(2 + NSIG) * (size_t)NFFT * sizeof(float2);
    if (ws_size < need) {
        dim3 g((TT + 255) / 256, 32);
        k_direct<<<g, 256, 0, stream>>>(x, ir, wet, out);
        return;
    }

    float2* Ht   = (float2*)d_ws;
    float2* irA  = Ht + NFFT;
    float2* bufA = irA + NFFT;

    k_stage1<<<dim3(N2 / C1, NSIG + 1), 1024, 0, stream>>>(x, ir, bufA, irA);
    k_stage2_ir<<<dim3(N1 / R2), 1024, 0, stream>>>(irA, Ht);
    k_stage2<<<dim3(NSIG * N1 / R2), 1024, 0, stream>>>(bufA, bufA, Ht);
    k_stage3<<<dim3(N2 / C1, NSIG), 1024, 0, stream>>>(bufA, x, wet, out);
}

// Round 4
// 210.619 us; speedup vs baseline: 1.0306x; 1.0090x over previous
//
#include <hip/hip_runtime.h>
#include <math.h>

constexpr int NFFT = 524288;   // 2^19 >= T + L - 1 = 485099
constexpr int N1   = 512;      // column FFT length (strided dim)
constexpr int N2   = 1024;     // row FFT length (contiguous dim)
constexpr int TT   = 441000;   // multiple of 4
constexpr int IRL  = 44100;    // multiple of 4
constexpr int NSIG = 16;       // 32 real batches packed as 16 complex signals
constexpr int C1   = 16;       // columns per block in stage1/3
constexpr int TILE = N1 * C1;  // 8192 complex: one (all-k1 x 16-n2) tile

// bufA/irA layout is TILED: addr = (n2/16)*TILE + k1*16 + (n2%16).
// Writer (stage1) and readers (stage2 gather, stage3 full tile) all touch
// >=128B contiguous segments -> full HBM lines. Ht stays row-major [k1][n2].

// -2*pi/NFFT
constexpr float ANG0   = -1.1984224905891939e-5f;
constexpr float NTWOPI = -6.2831853071795864769f;

__device__ inline float2 cmulf(float2 a, float2 b) {
    return make_float2(a.x * b.x - a.y * b.y, a.x * b.y + a.y * b.x);
}
__device__ inline float2 cadd(float2 a, float2 b) { return make_float2(a.x + b.x, a.y + b.y); }
__device__ inline float2 csub(float2 a, float2 b) { return make_float2(a.x - b.x, a.y - b.y); }

// Radix-4 Stockham butterfly (validated). Outputs to q+4sp+{0,s,2s,3s},
// twiddles W^{ps},W^{2ps},W^{3ps}; cross term -i fwd / +i inv (caller conjugates w).
template<bool INV>
__device__ inline void bfly4(const float2* u, float2 w1, float2 w2, float2 w3, float2* o) {
    float2 t0 = cadd(u[0], u[2]);
    float2 t1 = csub(u[0], u[2]);
    float2 t2 = cadd(u[1], u[3]);
    float2 t3 = csub(u[1], u[3]);
    float2 r3 = INV ? make_float2(-t3.y, t3.x) : make_float2(t3.y, -t3.x);
    o[0] = cadd(t0, t2);
    o[1] = cmulf(cadd(t1, r3), w1);
    o[2] = cmulf(csub(t0, t2), w2);
    o[3] = cmulf(csub(t1, r3), w3);
}
// Unit-twiddle variant (s = L/4 final pass: p=0 -> w=1).
template<bool INV>
__device__ inline void bfly4_nw(const float2* u, float2* o) {
    float2 t0 = cadd(u[0], u[2]);
    float2 t1 = csub(u[0], u[2]);
    float2 t2 = cadd(u[1], u[3]);
    float2 t3 = csub(u[1], u[3]);
    float2 r3 = INV ? make_float2(-t3.y, t3.x) : make_float2(t3.y, -t3.x);
    o[0] = cadd(t0, t2);
    o[1] = cadd(t1, r3);
    o[2] = csub(t0, t2);
    o[3] = csub(t1, r3);
}

// First 4 radix-4 passes (s=1,4,16,64) of the 512-FFT over 16 XOR-swizzled
// sequences; 1024 threads: thread owns butterfly f = t&127 of seqs cb, cb+8.
template<bool INV>
__device__ void fft512_4p(float2* buf, const float2* __restrict__ tw, int tid) {
    const int f  = tid & 127;
    const int cb = tid >> 7;          // 0..7 (wave-uniform)
    int s = 1, logs = 0;
#pragma unroll
    for (int pass = 0; pass < 4; ++pass) {
        const int p = f >> logs;
        const int q = f & (s - 1);
        const int wb = q + 4 * s * p;
        const int e = p * s;
        float2 w1 = tw[e], w2 = tw[2 * e], w3 = tw[3 * e];
        if (INV) { w1.y = -w1.y; w2.y = -w2.y; w3.y = -w3.y; }
        float2 u[2][4];
#pragma unroll
        for (int k = 0; k < 2; ++k) {
            const int c = cb + 8 * k;
            float2* sb = buf + c * N1;
#pragma unroll
            for (int j = 0; j < 4; ++j) u[k][j] = sb[(f + 128 * j) ^ c];
        }
        __syncthreads();
#pragma unroll
        for (int k = 0; k < 2; ++k) {
            const int c = cb + 8 * k;
            float2* sb = buf + c * N1;
            float2 o[4];
            bfly4<INV>(u[k], w1, w2, w3, o);
            sb[wb ^ c]           = o[0];
            sb[(wb + s) ^ c]     = o[1];
            sb[(wb + 2 * s) ^ c] = o[2];
            sb[(wb + 3 * s) ^ c] = o[3];
        }
        __syncthreads();
        s <<= 2; logs += 2;
    }
}

// Radix-4 passes [FIRST, FIRST+COUNT) of the 1024-FFT over one row in LDS.
// Works for any blockDim covering f = tid&255 (r = tid>>8 rows of N2).
template<bool INV, int FIRST, int COUNT>
__device__ void fft1024_mid(float2* buf, const float2* __restrict__ tw, int tid) {
    const int f = tid & 255;
    const int r = tid >> 8;
    float2* sb = buf + r * N2;
    int s = 1 << (2 * FIRST), logs = 2 * FIRST;
#pragma unroll
    for (int pass = 0; pass < COUNT; ++pass) {
        const int p = f >> logs;
        const int q = f & (s - 1);
        const int wb = q + 4 * s * p;
        const int e = p * s;
        float2 w1 = tw[e], w2 = tw[2 * e], w3 = tw[3 * e];
        if (INV) { w1.y = -w1.y; w2.y = -w2.y; w3.y = -w3.y; }
        float2 u[4];
#pragma unroll
        for (int j = 0; j < 4; ++j) u[j] = sb[f + 256 * j];
        __syncthreads();
        float2 o[4];
        bfly4<INV>(u, w1, w2, w3, o);
        sb[wb]         = o[0];
        sb[wb + s]     = o[1];
        sb[wb + 2 * s] = o[2];
        sb[wb + 3 * s] = o[3];
        __syncthreads();
        s <<= 2; logs += 2;
    }
}

// Stage 1 (forward): 512-pt column FFTs (stride N2) for 16 consecutive n2 per
// block; float4 loads; final radix-2 fused with inter-stage twiddle + store.
// Stores to the TILED layout: this block's tile is contiguous (64 KB).
__global__ __launch_bounds__(1024) void k_stage1(const float* __restrict__ x,
                                                 const float* __restrict__ ir,
                                                 float2* __restrict__ bufA,
                                                 float2* __restrict__ irA) {
    __shared__ float2 buf[C1 * N1];   // 64 KB
    __shared__ float2 tw[N1];         // 4 KB, W_512^j
    const int sig  = blockIdx.y;
    const int col0 = blockIdx.x * C1;
    const int tid  = threadIdx.x;

    if (tid < N1) {
        float sn, cs;
        __sincosf(NTWOPI * (float)tid * (1.0f / (float)N1), &sn, &cs);
        tw[tid] = make_float2(cs, sn);
    }

    if (sig < NSIG) {
        const float* xa = x + (size_t)(2 * sig) * TT;
        const float* xb = xa + TT;
#pragma unroll
        for (int it = 0; it < 2; ++it) {
            const int qi = tid + 1024 * it;     // 2048 quads
            const int n1 = qi >> 2;
            const int c4 = (qi & 3) * 4;
            const int n  = n1 * N2 + col0 + c4; // n % 4 == 0
            float4 a4 = make_float4(0.f, 0.f, 0.f, 0.f);
            float4 b4 = a4;
            if (n < TT) {
                a4 = *(const float4*)(xa + n);
                b4 = *(const float4*)(xb + n);
            }
            buf[(c4 + 0) * N1 + (n1 ^ (c4 + 0))] = make_float2(a4.x, b4.x);
            buf[(c4 + 1) * N1 + (n1 ^ (c4 + 1))] = make_float2(a4.y, b4.y);
            buf[(c4 + 2) * N1 + (n1 ^ (c4 + 2))] = make_float2(a4.z, b4.z);
            buf[(c4 + 3) * N1 + (n1 ^ (c4 + 3))] = make_float2(a4.w, b4.w);
        }
    } else {
#pragma unroll
        for (int it = 0; it < 2; ++it) {
            const int qi = tid + 1024 * it;
            const int n1 = qi >> 2;
            const int c4 = (qi & 3) * 4;
            const int n  = n1 * N2 + col0 + c4;
            float4 a4 = make_float4(0.f, 0.f, 0.f, 0.f);
            if (n < IRL) a4 = *(const float4*)(ir + n);
            buf[(c4 + 0) * N1 + (n1 ^ (c4 + 0))] = make_float2(a4.x, 0.f);
            buf[(c4 + 1) * N1 + (n1 ^ (c4 + 1))] = make_float2(a4.y, 0.f);
            buf[(c4 + 2) * N1 + (n1 ^ (c4 + 2))] = make_float2(a4.z, 0.f);
            buf[(c4 + 3) * N1 + (n1 ^ (c4 + 3))] = make_float2(a4.w, 0.f);
        }
    }
    __syncthreads();

    fft512_4p<false>(buf, tw, tid);

    // fused: final radix-2 (slots f / f+256) + W_N^{n2*k1} twiddle + store.
    float2* dst = (sig < NSIG) ? (bufA + (size_t)sig * NFFT) : irA;
    float2* dstt = dst + (size_t)blockIdx.x * TILE;   // this block's tile
    const int c  = tid & 15;
    const int fr = tid >> 4;          // 0..63
    const int n2 = col0 + c;
    float2 w0, s64, s256;
    {
        float sn, cs;
        __sincosf(ANG0 * (float)(n2 * fr), &sn, &cs);   w0   = make_float2(cs, sn);
        __sincosf(ANG0 * (float)(n2 * 64), &sn, &cs);   s64  = make_float2(cs, sn);
        __sincosf(ANG0 * (float)(n2 * 256), &sn, &cs);  s256 = make_float2(cs, sn);
    }
#pragma unroll
    for (int it = 0; it < 4; ++it) {
        const int fo = fr + 64 * it;  // 0..255
        float2 a = buf[c * N1 + (fo ^ c)];
        float2 b = buf[c * N1 + ((fo + 256) ^ c)];
        float2 X0 = cadd(a, b);
        float2 X1 = csub(a, b);
        dstt[fo * C1 + c]         = cmulf(X0, w0);
        dstt[(fo + 256) * C1 + c] = cmulf(X1, cmulf(w0, s256));
        w0 = cmulf(w0, s64);
    }
}

// Stage 2, IR path: forward 1024-FFT only -> Ht (transposed spectrum, row-major).
// 256-thread blocks, one row each (16 KB LDS -> 8 blocks/CU phase overlap).
__global__ __launch_bounds__(256) void k_stage2_ir(const float2* __restrict__ src,
                                                   float2* __restrict__ dst) {
    __shared__ float2 buf[N2];        // 8 KB
    __shared__ float2 tw[N2];         // 8 KB, W_1024^j
    const int k1  = blockIdx.x;
    const int tid = threadIdx.x;      // 0..255

#pragma unroll
    for (int it = 0; it < 4; ++it) {
        const int j = tid + 256 * it;
        float sn, cs;
        __sincosf(NTWOPI * (float)j * (1.0f / (float)N2), &sn, &cs);
        tw[j] = make_float2(cs, sn);
    }
#pragma unroll
    for (int it = 0; it < 2; ++it) {
        const int qi   = tid + 256 * it;    // 512 float4 = one row
        const int tile = qi >> 3;           // 0..63
        const int q8   = qi & 7;            // float4 within 128B tile-row seg
        ((float4*)buf)[qi] =
            ((const float4*)src)[(size_t)tile * (TILE / 2) + k1 * 8 + q8];
    }
    __syncthreads();

    fft1024_mid<false, 0, 4>(buf, tw, tid);

    const int f = tid;
    float2 u[4], o[4];
#pragma unroll
    for (int j = 0; j < 4; ++j) u[j] = buf[f + 256 * j];
    bfly4_nw<false>(u, o);
#pragma unroll
    for (int j = 0; j < 4; ++j)
        dst[(size_t)k1 * N2 + f + 256 * j] = o[j];
}

// Stage 2: fwd 1024-FFT, * Ht, inv 1024-FFT, conj inter-stage twiddle, store.
// 256-thread blocks, one row each (16 KB LDS -> 8 blocks/CU so independent
// blocks interleave load/FFT/store phases). Ht prefetched to regs before the
// forward FFT. IN-PLACE safe: row fully in LDS before any write to it.
__global__ __launch_bounds__(256) void k_stage2(const float2* __restrict__ src,
                                                float2* __restrict__ dst,
                                                const float2* __restrict__ Ht) {
    __shared__ float2 buf[N2];        // 8 KB
    __shared__ float2 tw[N2];         // 8 KB
    const int flat = blockIdx.x;      // = sig*N1 + k1
    const int sg   = flat >> 9;
    const int k1   = flat & (N1 - 1);
    const int tid  = threadIdx.x;     // 0..255

#pragma unroll
    for (int it = 0; it < 4; ++it) {
        const int j = tid + 256 * it;
        float sn, cs;
        __sincosf(NTWOPI * (float)j * (1.0f / (float)N2), &sn, &cs);
        tw[j] = make_float2(cs, sn);
    }
#pragma unroll
    for (int it = 0; it < 2; ++it) {
        const int qi   = tid + 256 * it;
        const int tile = qi >> 3;
        const int q8   = qi & 7;
        ((float4*)buf)[qi] =
            ((const float4*)src)[(size_t)sg * (NFFT / 2) +
                                 (size_t)tile * (TILE / 2) + k1 * 8 + q8];
    }
    // Ht prefetch into registers; consumed after the forward FFT.
    const int f = tid;
    float2 h[4];
#pragma unroll
    for (int j = 0; j < 4; ++j) h[j] = Ht[(size_t)k1 * N2 + f + 256 * j];
    __syncthreads();

    fft1024_mid<false, 0, 4>(buf, tw, tid);

    {   // fwd p4 (unit tw) -> * Ht -> inv p0 (conj W_1024^{f,2f,3f}), in regs
        float2 u[4];
#pragma unroll
        for (int j = 0; j < 4; ++j) u[j] = buf[f + 256 * j];
        __syncthreads();   // WAR guard
        float2 w1 = tw[f], w2 = tw[2 * f], w3 = tw[3 * f];
        w1.y = -w1.y; w2.y = -w2.y; w3.y = -w3.y;
        float2 o[4], v[4], o2[4];
        bfly4_nw<false>(u, o);
#pragma unroll
        for (int j = 0; j < 4; ++j) v[j] = cmulf(o[j], h[j]);
        bfly4<true>(v, w1, w2, w3, o2);
#pragma unroll
        for (int j = 0; j < 4; ++j) buf[4 * f + j] = o2[j];   // wb=4f, s=1
        __syncthreads();
    }

    fft1024_mid<true, 1, 3>(buf, tw, tid);   // inv passes s=4,16,64

    // inv final pass (s=256, unit tw) + conj twiddle recurrence + store:
    // W^{-k1(f+256j)} = W^{-k1 f} * (W^{-256 k1})^j
    float2 u[4], o[4];
#pragma unroll
    for (int j = 0; j < 4; ++j) u[j] = buf[f + 256 * j];
    bfly4_nw<true>(u, o);
    float2 w, st;
    {
        float sn, cs;
        __sincosf(-ANG0 * (float)(f * k1), &sn, &cs);   w  = make_float2(cs, sn);
        __sincosf(-ANG0 * (float)(256 * k1), &sn, &cs); st = make_float2(cs, sn);
    }
    float2* db = dst + (size_t)sg * NFFT;
#pragma unroll
    for (int j = 0; j < 4; ++j) {
        const int n2 = f + 256 * j;
        db[(size_t)(n2 >> 4) * TILE + k1 * C1 + (n2 & 15)] = cmulf(o[j], w);
        w = cmulf(w, st);
    }
}

// Stage 3 (inverse): 512-pt column IFFTs; final radix-2 fused with unpack,
// wet/dry mix and float4 stores. Reads its TILED bufA tile contiguously;
// x is prefetched into registers BEFORE the FFT so its HBM latency hides
// under the LDS compute phase.
__global__ __launch_bounds__(1024) void k_stage3(const float2* __restrict__ bufB,
                                                 const float* __restrict__ x,
                                                 const float* __restrict__ wet_param,
                                                 float* __restrict__ out) {
    __shared__ float2 buf[C1 * N1];   // 64 KB
    __shared__ float2 tw[N1];         // 4 KB
    const int sig  = blockIdx.y;
    const int col0 = blockIdx.x * C1;
    const int tid  = threadIdx.x;

    if (tid < N1) {
        float sn, cs;
        __sincosf(NTWOPI * (float)tid * (1.0f / (float)N1), &sn, &cs);
        tw[tid] = make_float2(cs, sn);
    }

    const float2* st = bufB + (size_t)sig * NFFT + (size_t)blockIdx.x * TILE;
    {
        const int cp  = tid & 7;      // float4 within tile-row
        const int k1b = tid >> 3;     // 0..127
#pragma unroll
        for (int it = 0; it < 4; ++it) {
            const int k1 = k1b + 128 * it;
            float4 v = ((const float4*)st)[k1 * 8 + cp];   // contiguous tile
            const int ca = 2 * cp, cb2 = 2 * cp + 1;
            buf[ca * N1 + (k1 ^ ca)]   = make_float2(v.x, v.y);
            buf[cb2 * N1 + (k1 ^ cb2)] = make_float2(v.z, v.w);
        }
    }

    // ---- x prefetch into registers (overlaps the FFT below) ----
    const float* xa = x + (size_t)(2 * sig) * TT;
    const float* xb = xa + TT;
    const int c4 = (tid & 3) * 4;
    const int fo = tid >> 2;          // 0..255
    const int n0 = fo * N2 + col0 + c4;
    const int n1 = (fo + 256) * N2 + col0 + c4;
    float4 xa0 = make_float4(0.f, 0.f, 0.f, 0.f), xb0 = xa0, xa1 = xa0, xb1 = xa0;
    if (n0 < TT) { xa0 = *(const float4*)(xa + n0); xb0 = *(const float4*)(xb + n0); }
    if (n1 < TT) { xa1 = *(const float4*)(xa + n1); xb1 = *(const float4*)(xb + n1); }

    __syncthreads();

    fft512_4p<true>(buf, tw, tid);

    const float wet = 1.0f / (1.0f + expf(-wet_param[0]));
    const float dry = 1.0f - wet;
    const float ws  = wet * (1.0f / (float)NFFT);

    float* oa = out + (size_t)(2 * sig) * TT;
    float* ob = oa + TT;

    float2 y0[4], y1[4];
#pragma unroll
    for (int jj = 0; jj < 4; ++jj) {
        const int c = c4 + jj;
        float2 a = buf[c * N1 + (fo ^ c)];
        float2 b = buf[c * N1 + ((fo + 256) ^ c)];
        y0[jj] = cadd(a, b);          // time row fo
        y1[jj] = csub(a, b);          // time row fo+256
    }
    if (n0 < TT) {
        float4 ra, rb2;
        ra.x = dry * xa0.x + ws * y0[0].x;
        ra.y = dry * xa0.y + ws * y0[1].x;
        ra.z = dry * xa0.z + ws * y0[2].x;
        ra.w = dry * xa0.w + ws * y0[3].x;
        rb2.x = dry * xb0.x + ws * y0[0].y;
        rb2.y = dry * xb0.y + ws * y0[1].y;
        rb2.z = dry * xb0.z + ws * y0[2].y;
        rb2.w = dry * xb0.w + ws * y0[3].y;
        *(float4*)(oa + n0) = ra;
        *(float4*)(ob + n0) = rb2;
    }
    if (n1 < TT) {
        float4 ra, rb2;
        ra.x = dry * xa1.x + ws * y1[0].x;
        ra.y = dry * xa1.y + ws * y1[1].x;
        ra.z = dry * xa1.z + ws * y1[2].x;
        ra.w = dry * xa1.w + ws * y1[3].x;
        rb2.x = dry * xb1.x + ws * y1[0].y;
        rb2.y = dry * xb1.y + ws * y1[1].y;
        rb2.z = dry * xb1.z + ws * y1[2].y;
        rb2.w = dry * xb1.w + ws * y1[3].y;
        *(float4*)(oa + n1) = ra;
        *(float4*)(ob + n1) = rb2;
    }
}

// Correctness fallback if workspace is too small: direct time-domain conv.
__global__ __launch_bounds__(256) void k_direct(const float* __restrict__ x,
                                                const float* __restrict__ ir,
                                                const float* __restrict__ wet_param,
                                                float* __restrict__ out) {
    __shared__ float irs[1024];
    const int b = blockIdx.y;
    const int n = blockIdx.x * 256 + threadIdx.x;
    float acc = 0.0f;
    for (int k0 = 0; k0 < IRL; k0 += 1024) {
        __syncthreads();
        for (int j = threadIdx.x; j < 1024; j += 256) {
            const int k = k0 + j;
            irs[j] = (k < IRL) ? ir[k] : 0.0f;
        }
        __syncthreads();
        if (n < TT) {
            const int kend = min(1024, n - k0 + 1);
            for (int k = 0; k < kend; ++k)
                acc += irs[k] * x[(size_t)b * TT + (n - k0 - k)];
        }
    }
    if (n < TT) {
        const float wet = 1.0f / (1.0f + expf(-wet_param[0]));
        out[(size_t)b * TT + n] = (1.0f - wet) * x[(size_t)b * TT + n] + wet * acc;
    }
}

extern "C" void kernel_launch(void* const* d_in, const int* in_sizes, int n_in,
                              void* d_out, int out_size, void* d_ws, size_t ws_size,
                              hipStream_t stream) {
    (void)in_sizes; (void)n_in; (void)out_size;
    const float* x   = (const float*)d_in[0];
    const float* ir  = (const float*)d_in[1];
    const float* wet = (const float*)d_in[2];
    float* out = (float*)d_out;

    // ws: Ht(NFFT) + irA(NFFT) + bufA(16*NFFT); stage2 runs IN-PLACE on bufA.
    const size_t need = (size_t)(2 + NSIG) * (size_t)NFFT * sizeof(float2);
    if (ws_size < need) {
        dim3 g((TT + 255) / 256, 32);
        k_direct<<<g, 256, 0, stream>>>(x, ir, wet, out);
        return;
    }

    float2* Ht   = (float2*)d_ws;
    float2* irA  = Ht + NFFT;
    float2* bufA = irA + NFFT;

    k_stage1<<<dim3(N2 / C1, NSIG + 1), 1024, 0, stream>>>(x, ir, bufA, irA);
    k_stage2_ir<<<dim3(N1), 256, 0, stream>>>(irA, Ht);
    k_stage2<<<dim3(NSIG * N1), 256, 0, stream>>>(bufA, bufA, Ht);
    k_stage3<<<dim3(N2 / C1, NSIG), 1024, 0, stream>>>(bufA, x, wet, out);
}

// Round 5
// 195.441 us; speedup vs baseline: 1.1106x; 1.0777x over previous
//
#include <hip/hip_runtime.h>
#include <math.h>

constexpr int NFFT = 524288;   // 2^19 >= T + L - 1 = 485099
constexpr int N1   = 512;      // column FFT length (strided dim)
constexpr int N2   = 1024;     // row FFT length (contiguous dim)
constexpr int TT   = 441000;   // multiple of 4
constexpr int IRL  = 44100;    // multiple of 4
constexpr int NSIG = 16;       // 32 real batches packed as 16 complex signals
constexpr int C1   = 16;       // columns per block in stage1/3
constexpr int TILE = N1 * C1;  // 8192 complex: one (all-k1 x 16-n2) tile

// bufA/irA layout is TILED: addr = (n2/16)*TILE + k1*16 + (n2%16).
// Ht stores H' = dry + wet*H (dry path folded into the spectrum, FFT(delta)=1),
// so stage3 needs neither x nor wet: out = IFFT[X*H']/NFFT.

// -2*pi/NFFT
constexpr float ANG0   = -1.1984224905891939e-5f;
constexpr float NTWOPI = -6.2831853071795864769f;

__device__ inline float2 cmulf(float2 a, float2 b) {
    return make_float2(a.x * b.x - a.y * b.y, a.x * b.y + a.y * b.x);
}
__device__ inline float2 cadd(float2 a, float2 b) { return make_float2(a.x + b.x, a.y + b.y); }
__device__ inline float2 csub(float2 a, float2 b) { return make_float2(a.x - b.x, a.y - b.y); }

// Radix-4 Stockham butterfly (validated). Outputs to q+4sp+{0,s,2s,3s},
// twiddles W^{ps},W^{2ps},W^{3ps}; cross term -i fwd / +i inv (caller conjugates w).
template<bool INV>
__device__ inline void bfly4(const float2* u, float2 w1, float2 w2, float2 w3, float2* o) {
    float2 t0 = cadd(u[0], u[2]);
    float2 t1 = csub(u[0], u[2]);
    float2 t2 = cadd(u[1], u[3]);
    float2 t3 = csub(u[1], u[3]);
    float2 r3 = INV ? make_float2(-t3.y, t3.x) : make_float2(t3.y, -t3.x);
    o[0] = cadd(t0, t2);
    o[1] = cmulf(cadd(t1, r3), w1);
    o[2] = cmulf(csub(t0, t2), w2);
    o[3] = cmulf(csub(t1, r3), w3);
}
// Unit-twiddle variant (s = L/4 final pass: p=0 -> w=1).
template<bool INV>
__device__ inline void bfly4_nw(const float2* u, float2* o) {
    float2 t0 = cadd(u[0], u[2]);
    float2 t1 = csub(u[0], u[2]);
    float2 t2 = cadd(u[1], u[3]);
    float2 t3 = csub(u[1], u[3]);
    float2 r3 = INV ? make_float2(-t3.y, t3.x) : make_float2(t3.y, -t3.x);
    o[0] = cadd(t0, t2);
    o[1] = cadd(t1, r3);
    o[2] = csub(t0, t2);
    o[3] = csub(t1, r3);
}

// First 4 radix-4 passes (s=1,4,16,64) of the 512-FFT over 16 XOR-swizzled
// sequences; 1024 threads: thread owns butterfly f = t&127 of seqs cb, cb+8.
template<bool INV>
__device__ void fft512_4p(float2* buf, const float2* __restrict__ tw, int tid) {
    const int f  = tid & 127;
    const int cb = tid >> 7;          // 0..7 (wave-uniform)
    int s = 1, logs = 0;
#pragma unroll
    for (int pass = 0; pass < 4; ++pass) {
        const int p = f >> logs;
        const int q = f & (s - 1);
        const int wb = q + 4 * s * p;
        const int e = p * s;
        float2 w1 = tw[e], w2 = tw[2 * e], w3 = tw[3 * e];
        if (INV) { w1.y = -w1.y; w2.y = -w2.y; w3.y = -w3.y; }
        float2 u[2][4];
#pragma unroll
        for (int k = 0; k < 2; ++k) {
            const int c = cb + 8 * k;
            float2* sb = buf + c * N1;
#pragma unroll
            for (int j = 0; j < 4; ++j) u[k][j] = sb[(f + 128 * j) ^ c];
        }
        __syncthreads();
#pragma unroll
        for (int k = 0; k < 2; ++k) {
            const int c = cb + 8 * k;
            float2* sb = buf + c * N1;
            float2 o[4];
            bfly4<INV>(u[k], w1, w2, w3, o);
            sb[wb ^ c]           = o[0];
            sb[(wb + s) ^ c]     = o[1];
            sb[(wb + 2 * s) ^ c] = o[2];
            sb[(wb + 3 * s) ^ c] = o[3];
        }
        __syncthreads();
        s <<= 2; logs += 2;
    }
}

// Radix-4 passes [FIRST, FIRST+COUNT) of the 1024-FFT over one row in LDS.
// Works for any blockDim covering f = tid&255 (r = tid>>8 rows of N2).
template<bool INV, int FIRST, int COUNT>
__device__ void fft1024_mid(float2* buf, const float2* __restrict__ tw, int tid) {
    const int f = tid & 255;
    const int r = tid >> 8;
    float2* sb = buf + r * N2;
    int s = 1 << (2 * FIRST), logs = 2 * FIRST;
#pragma unroll
    for (int pass = 0; pass < COUNT; ++pass) {
        const int p = f >> logs;
        const int q = f & (s - 1);
        const int wb = q + 4 * s * p;
        const int e = p * s;
        float2 w1 = tw[e], w2 = tw[2 * e], w3 = tw[3 * e];
        if (INV) { w1.y = -w1.y; w2.y = -w2.y; w3.y = -w3.y; }
        float2 u[4];
#pragma unroll
        for (int j = 0; j < 4; ++j) u[j] = sb[f + 256 * j];
        __syncthreads();
        float2 o[4];
        bfly4<INV>(u, w1, w2, w3, o);
        sb[wb]         = o[0];
        sb[wb + s]     = o[1];
        sb[wb + 2 * s] = o[2];
        sb[wb + 3 * s] = o[3];
        __syncthreads();
        s <<= 2; logs += 2;
    }
}

// Stage 1 (forward): 512-pt column FFTs (stride N2) for 16 consecutive n2 per
// block; float4 loads; final radix-2 fused with inter-stage twiddle + store.
// Stores to the TILED layout: this block's tile is contiguous (64 KB).
__global__ __launch_bounds__(1024) void k_stage1(const float* __restrict__ x,
                                                 const float* __restrict__ ir,
                                                 float2* __restrict__ bufA,
                                                 float2* __restrict__ irA) {
    __shared__ float2 buf[C1 * N1];   // 64 KB
    __shared__ float2 tw[N1];         // 4 KB, W_512^j
    const int sig  = blockIdx.y;
    const int col0 = blockIdx.x * C1;
    const int tid  = threadIdx.x;

    if (tid < N1) {
        float sn, cs;
        __sincosf(NTWOPI * (float)tid * (1.0f / (float)N1), &sn, &cs);
        tw[tid] = make_float2(cs, sn);
    }

    if (sig < NSIG) {
        const float* xa = x + (size_t)(2 * sig) * TT;
        const float* xb = xa + TT;
#pragma unroll
        for (int it = 0; it < 2; ++it) {
            const int qi = tid + 1024 * it;     // 2048 quads
            const int n1 = qi >> 2;
            const int c4 = (qi & 3) * 4;
            const int n  = n1 * N2 + col0 + c4; // n % 4 == 0
            float4 a4 = make_float4(0.f, 0.f, 0.f, 0.f);
            float4 b4 = a4;
            if (n < TT) {
                a4 = *(const float4*)(xa + n);
                b4 = *(const float4*)(xb + n);
            }
            buf[(c4 + 0) * N1 + (n1 ^ (c4 + 0))] = make_float2(a4.x, b4.x);
            buf[(c4 + 1) * N1 + (n1 ^ (c4 + 1))] = make_float2(a4.y, b4.y);
            buf[(c4 + 2) * N1 + (n1 ^ (c4 + 2))] = make_float2(a4.z, b4.z);
            buf[(c4 + 3) * N1 + (n1 ^ (c4 + 3))] = make_float2(a4.w, b4.w);
        }
    } else {
#pragma unroll
        for (int it = 0; it < 2; ++it) {
            const int qi = tid + 1024 * it;
            const int n1 = qi >> 2;
            const int c4 = (qi & 3) * 4;
            const int n  = n1 * N2 + col0 + c4;
            float4 a4 = make_float4(0.f, 0.f, 0.f, 0.f);
            if (n < IRL) a4 = *(const float4*)(ir + n);
            buf[(c4 + 0) * N1 + (n1 ^ (c4 + 0))] = make_float2(a4.x, 0.f);
            buf[(c4 + 1) * N1 + (n1 ^ (c4 + 1))] = make_float2(a4.y, 0.f);
            buf[(c4 + 2) * N1 + (n1 ^ (c4 + 2))] = make_float2(a4.z, 0.f);
            buf[(c4 + 3) * N1 + (n1 ^ (c4 + 3))] = make_float2(a4.w, 0.f);
        }
    }
    __syncthreads();

    fft512_4p<false>(buf, tw, tid);

    // fused: final radix-2 (slots f / f+256) + W_N^{n2*k1} twiddle + store.
    float2* dst = (sig < NSIG) ? (bufA + (size_t)sig * NFFT) : irA;
    float2* dstt = dst + (size_t)blockIdx.x * TILE;   // this block's tile
    const int c  = tid & 15;
    const int fr = tid >> 4;          // 0..63
    const int n2 = col0 + c;
    float2 w0, s64, s256;
    {
        float sn, cs;
        __sincosf(ANG0 * (float)(n2 * fr), &sn, &cs);   w0   = make_float2(cs, sn);
        __sincosf(ANG0 * (float)(n2 * 64), &sn, &cs);   s64  = make_float2(cs, sn);
        __sincosf(ANG0 * (float)(n2 * 256), &sn, &cs);  s256 = make_float2(cs, sn);
    }
#pragma unroll
    for (int it = 0; it < 4; ++it) {
        const int fo = fr + 64 * it;  // 0..255
        float2 a = buf[c * N1 + (fo ^ c)];
        float2 b = buf[c * N1 + ((fo + 256) ^ c)];
        float2 X0 = cadd(a, b);
        float2 X1 = csub(a, b);
        dstt[fo * C1 + c]         = cmulf(X0, w0);
        dstt[(fo + 256) * C1 + c] = cmulf(X1, cmulf(w0, s256));
        w0 = cmulf(w0, s64);
    }
}

// Stage 2, IR path: forward 1024-FFT -> H, then store H' = dry + wet*H
// (dry/delta path folded into the spectrum). Row-major [k1][n2].
__global__ __launch_bounds__(256) void k_stage2_ir(const float2* __restrict__ src,
                                                   float2* __restrict__ dst,
                                                   const float* __restrict__ wet_param) {
    __shared__ float2 buf[N2];        // 8 KB
    __shared__ float2 tw[N2];         // 8 KB, W_1024^j
    const int k1  = blockIdx.x;
    const int tid = threadIdx.x;      // 0..255

#pragma unroll
    for (int it = 0; it < 4; ++it) {
        const int j = tid + 256 * it;
        float sn, cs;
        __sincosf(NTWOPI * (float)j * (1.0f / (float)N2), &sn, &cs);
        tw[j] = make_float2(cs, sn);
    }
#pragma unroll
    for (int it = 0; it < 2; ++it) {
        const int qi   = tid + 256 * it;    // 512 float4 = one row
        const int tile = qi >> 3;           // 0..63
        const int q8   = qi & 7;            // float4 within 128B tile-row seg
        ((float4*)buf)[qi] =
            ((const float4*)src)[(size_t)tile * (TILE / 2) + k1 * 8 + q8];
    }
    __syncthreads();

    fft1024_mid<false, 0, 4>(buf, tw, tid);

    const float wet = 1.0f / (1.0f + expf(-wet_param[0]));
    const float dry = 1.0f - wet;

    const int f = tid;
    float2 u[4], o[4];
#pragma unroll
    for (int j = 0; j < 4; ++j) u[j] = buf[f + 256 * j];
    bfly4_nw<false>(u, o);
#pragma unroll
    for (int j = 0; j < 4; ++j)
        dst[(size_t)k1 * N2 + f + 256 * j] =
            make_float2(dry + wet * o[j].x, wet * o[j].y);
}

// Stage 2: fwd 1024-FFT, * H', inv 1024-FFT, conj inter-stage twiddle, store.
// 256-thread blocks, one row each (16 KB LDS -> 8 blocks/CU so independent
// blocks interleave load/FFT/store phases). H' prefetched to regs before the
// forward FFT. IN-PLACE safe: row fully in LDS before any write to it.
__global__ __launch_bounds__(256) void k_stage2(const float2* __restrict__ src,
                                                float2* __restrict__ dst,
                                                const float2* __restrict__ Ht) {
    __shared__ float2 buf[N2];        // 8 KB
    __shared__ float2 tw[N2];         // 8 KB
    const int flat = blockIdx.x;      // = sig*N1 + k1
    const int sg   = flat >> 9;
    const int k1   = flat & (N1 - 1);
    const int tid  = threadIdx.x;     // 0..255

#pragma unroll
    for (int it = 0; it < 4; ++it) {
        const int j = tid + 256 * it;
        float sn, cs;
        __sincosf(NTWOPI * (float)j * (1.0f / (float)N2), &sn, &cs);
        tw[j] = make_float2(cs, sn);
    }
#pragma unroll
    for (int it = 0; it < 2; ++it) {
        const int qi   = tid + 256 * it;
        const int tile = qi >> 3;
        const int q8   = qi & 7;
        ((float4*)buf)[qi] =
            ((const float4*)src)[(size_t)sg * (NFFT / 2) +
                                 (size_t)tile * (TILE / 2) + k1 * 8 + q8];
    }
    // H' prefetch into registers; consumed after the forward FFT.
    const int f = tid;
    float2 h[4];
#pragma unroll
    for (int j = 0; j < 4; ++j) h[j] = Ht[(size_t)k1 * N2 + f + 256 * j];
    __syncthreads();

    fft1024_mid<false, 0, 4>(buf, tw, tid);

    {   // fwd p4 (unit tw) -> * H' -> inv p0 (conj W_1024^{f,2f,3f}), in regs
        float2 u[4];
#pragma unroll
        for (int j = 0; j < 4; ++j) u[j] = buf[f + 256 * j];
        __syncthreads();   // WAR guard
        float2 w1 = tw[f], w2 = tw[2 * f], w3 = tw[3 * f];
        w1.y = -w1.y; w2.y = -w2.y; w3.y = -w3.y;
        float2 o[4], v[4], o2[4];
        bfly4_nw<false>(u, o);
#pragma unroll
        for (int j = 0; j < 4; ++j) v[j] = cmulf(o[j], h[j]);
        bfly4<true>(v, w1, w2, w3, o2);
#pragma unroll
        for (int j = 0; j < 4; ++j) buf[4 * f + j] = o2[j];   // wb=4f, s=1
        __syncthreads();
    }

    fft1024_mid<true, 1, 3>(buf, tw, tid);   // inv passes s=4,16,64

    // inv final pass (s=256, unit tw) + conj twiddle recurrence + store:
    // W^{-k1(f+256j)} = W^{-k1 f} * (W^{-256 k1})^j
    float2 u[4], o[4];
#pragma unroll
    for (int j = 0; j < 4; ++j) u[j] = buf[f + 256 * j];
    bfly4_nw<true>(u, o);
    float2 w, st;
    {
        float sn, cs;
        __sincosf(-ANG0 * (float)(f * k1), &sn, &cs);   w  = make_float2(cs, sn);
        __sincosf(-ANG0 * (float)(256 * k1), &sn, &cs); st = make_float2(cs, sn);
    }
    float2* db = dst + (size_t)sg * NFFT;
#pragma unroll
    for (int j = 0; j < 4; ++j) {
        const int n2 = f + 256 * j;
        db[(size_t)(n2 >> 4) * TILE + k1 * C1 + (n2 & 15)] = cmulf(o[j], w);
        w = cmulf(w, st);
    }
}

// Stage 3 (inverse): 512-pt column IFFTs; final radix-2 fused with unpack,
// 1/NFFT scale and float4 stores. Dry path already folded into H', so no
// x read and no wet param here. Reads its TILED bufA tile contiguously.
__global__ __launch_bounds__(1024) void k_stage3(const float2* __restrict__ bufB,
                                                 float* __restrict__ out) {
    __shared__ float2 buf[C1 * N1];   // 64 KB
    __shared__ float2 tw[N1];         // 4 KB
    const int sig  = blockIdx.y;
    const int col0 = blockIdx.x * C1;
    const int tid  = threadIdx.x;

    if (tid < N1) {
        float sn, cs;
        __sincosf(NTWOPI * (float)tid * (1.0f / (float)N1), &sn, &cs);
        tw[tid] = make_float2(cs, sn);
    }

    const float2* st = bufB + (size_t)sig * NFFT + (size_t)blockIdx.x * TILE;
    {
        const int cp  = tid & 7;      // float4 within tile-row
        const int k1b = tid >> 3;     // 0..127
#pragma unroll
        for (int it = 0; it < 4; ++it) {
            const int k1 = k1b + 128 * it;
            float4 v = ((const float4*)st)[k1 * 8 + cp];   // contiguous tile
            const int ca = 2 * cp, cb2 = 2 * cp + 1;
            buf[ca * N1 + (k1 ^ ca)]   = make_float2(v.x, v.y);
            buf[cb2 * N1 + (k1 ^ cb2)] = make_float2(v.z, v.w);
        }
    }
    __syncthreads();

    fft512_4p<true>(buf, tw, tid);

    const float ws = 1.0f / (float)NFFT;

    float* oa = out + (size_t)(2 * sig) * TT;
    float* ob = oa + TT;

    const int c4 = (tid & 3) * 4;
    const int fo = tid >> 2;          // 0..255
    float2 y0[4], y1[4];
#pragma unroll
    for (int jj = 0; jj < 4; ++jj) {
        const int c = c4 + jj;
        float2 a = buf[c * N1 + (fo ^ c)];
        float2 b = buf[c * N1 + ((fo + 256) ^ c)];
        y0[jj] = cadd(a, b);          // time row fo
        y1[jj] = csub(a, b);          // time row fo+256
    }
#pragma unroll
    for (int h = 0; h < 2; ++h) {
        const int row = fo + 256 * h;
        const int n   = row * N2 + col0 + c4;   // n % 4 == 0
        if (n < TT) {
            const float2* yy = h ? y1 : y0;
            float4 ra, rb2;
            ra.x = ws * yy[0].x;
            ra.y = ws * yy[1].x;
            ra.z = ws * yy[2].x;
            ra.w = ws * yy[3].x;
            rb2.x = ws * yy[0].y;
            rb2.y = ws * yy[1].y;
            rb2.z = ws * yy[2].y;
            rb2.w = ws * yy[3].y;
            *(float4*)(oa + n) = ra;
            *(float4*)(ob + n) = rb2;
        }
    }
}

// Correctness fallback if workspace is too small: direct time-domain conv.
__global__ __launch_bounds__(256) void k_direct(const float* __restrict__ x,
                                                const float* __restrict__ ir,
                                                const float* __restrict__ wet_param,
                                                float* __restrict__ out) {
    __shared__ float irs[1024];
    const int b = blockIdx.y;
    const int n = blockIdx.x * 256 + threadIdx.x;
    float acc = 0.0f;
    for (int k0 = 0; k0 < IRL; k0 += 1024) {
        __syncthreads();
        for (int j = threadIdx.x; j < 1024; j += 256) {
            const int k = k0 + j;
            irs[j] = (k < IRL) ? ir[k] : 0.0f;
        }
        __syncthreads();
        if (n < TT) {
            const int kend = min(1024, n - k0 + 1);
            for (int k = 0; k < kend; ++k)
                acc += irs[k] * x[(size_t)b * TT + (n - k0 - k)];
        }
    }
    if (n < TT) {
        const float wet = 1.0f / (1.0f + expf(-wet_param[0]));
        out[(size_t)b * TT + n] = (1.0f - wet) * x[(size_t)b * TT + n] + wet * acc;
    }
}

extern "C" void kernel_launch(void* const* d_in, const int* in_sizes, int n_in,
                              void* d_out, int out_size, void* d_ws, size_t ws_size,
                              hipStream_t stream) {
    (void)in_sizes; (void)n_in; (void)out_size;
    const float* x   = (const float*)d_in[0];
    const float* ir  = (const float*)d_in[1];
    const float* wet = (const float*)d_in[2];
    float* out = (float*)d_out;

    // ws: Ht(NFFT) + irA(NFFT) + bufA(16*NFFT); stage2 runs IN-PLACE on bufA.
    const size_t need = (size_t)(2 + NSIG) * (size_t)NFFT * sizeof(float2);
    if (ws_size < need) {
        dim3 g((TT + 255) / 256, 32);
        k_direct<<<g, 256, 0, stream>>>(x, ir, wet, out);
        return;
    }

    float2* Ht   = (float2*)d_ws;
    float2* irA  = Ht + NFFT;
    float2* bufA = irA + NFFT;

    k_stage1<<<dim3(N2 / C1, NSIG + 1), 1024, 0, stream>>>(x, ir, bufA, irA);
    k_stage2_ir<<<dim3(N1), 256, 0, stream>>>(irA, Ht, wet);
    k_stage2<<<dim3(NSIG * N1), 256, 0, stream>>>(bufA, bufA, Ht);
    k_stage3<<<dim3(N2 / C1, NSIG), 1024, 0, stream>>>(bufA, out);
}